// Round 1
// baseline (361.222 us; speedup 1.0000x reference)
//
#include <hip/hip_runtime.h>
#include <stdint.h>

typedef unsigned short u16;
typedef unsigned int   u32;
typedef __attribute__((ext_vector_type(8))) short short8;
typedef __attribute__((ext_vector_type(4))) float f32x4;
typedef __attribute__((ext_vector_type(8))) u16   u16x8;

// Problem constants: N=4, S=4096, E=1024, H=16, D=64
static constexpr size_t NX = (size_t)4 * 4096 * 1024;   // 16,777,216 x elems
static constexpr size_t NW = (size_t)1024 * 1024;       // 1,048,576 weight elems

// Workspace layout (bytes). energy aliases xb (xb dead after QK GEMMs + vs).
// Z2 aliases Qb (Qb dead after energy kernel). Peak ~113 MB.
static constexpr size_t OFF_XB   = 0;                   // 33,554,432  bf16 x
static constexpr size_t OFF_EN   = 0;                   // 16,777,216  f32 energy [4][4096][256]
static constexpr size_t OFF_QB   = 33554432;            // 33,554,432  bf16 Q  (later Z2)
static constexpr size_t OFF_KB   = 67108864;            // 33,554,432  bf16 K
static constexpr size_t OFF_WQB  = 100663296;           // 2,097,152
static constexpr size_t OFF_WKB  = 102760448;           // 2,097,152
static constexpr size_t OFF_WOB  = 104857600;           // 2,097,152
static constexpr size_t OFF_WVST = 106954752;           // 262,144  f32 [1024][64]
static constexpr size_t OFF_VS   = 107216896;           // 4,194,304 f32 [16384][64]
static constexpr size_t OFF_PMAX = 111411200;           // 65,536
static constexpr size_t OFF_PSUM = 111476736;           // 65,536
static constexpr size_t OFF_GMAX = 111542272;           // 4,096
static constexpr size_t OFF_INVZ = 111546368;           // 4,096
static constexpr size_t OFF_A    = 111550464;           // 1,048,576 f32 [16384][16]

static __device__ __forceinline__ u16 f2bf(float f) {
    u32 u = __builtin_bit_cast(u32, f);
    u += 0x7fffu + ((u >> 16) & 1u);        // RNE
    return (u16)(u >> 16);
}
static __device__ __forceinline__ float bf2f(u16 v) {
    u32 u = ((u32)v) << 16;
    return __builtin_bit_cast(float, u);
}

#if __has_builtin(__builtin_amdgcn_global_load_lds)
#define HAVE_GLOAD_LDS 1
static __device__ __forceinline__ void gload_lds16(const void* g, void* l) {
    __builtin_amdgcn_global_load_lds(
        (__attribute__((address_space(1))) void*)(uintptr_t)g,
        (__attribute__((address_space(3))) void*)(uintptr_t)l,
        16, 0, 0);
}
#endif

// ---------------------------------------------------------------------------
// fused fp32 -> bf16 conversion for x, Wq, Wk, Wo
__global__ __launch_bounds__(256)
void cvt_kernel(const float* __restrict__ x, const float* __restrict__ wq,
                const float* __restrict__ wk, const float* __restrict__ wo,
                u16* __restrict__ xb, u16* __restrict__ wqb,
                u16* __restrict__ wkb, u16* __restrict__ wob)
{
    size_t i = ((size_t)blockIdx.x * 256 + threadIdx.x) * 8;
    const float* s; u16* dst; size_t o;
    if (i < NX) { s = x; dst = xb; o = i; }
    else {
        size_t r = i - NX;
        int w = (int)(r >> 20);             // NW = 2^20
        o = r & (NW - 1);
        s   = (w == 0) ? wq  : (w == 1) ? wk  : wo;
        dst = (w == 0) ? wqb : (w == 1) ? wkb : wob;
    }
    f32x4 a = *(const f32x4*)&s[o];
    f32x4 c = *(const f32x4*)&s[o + 4];
    u16x8 v;
    v[0]=f2bf(a[0]); v[1]=f2bf(a[1]); v[2]=f2bf(a[2]); v[3]=f2bf(a[3]);
    v[4]=f2bf(c[0]); v[5]=f2bf(c[1]); v[6]=f2bf(c[2]); v[7]=f2bf(c[3]);
    *(u16x8*)&dst[o] = v;
}

// WvsT[e*64+d] = sum_h Wv[(h*64+d)*1024 + e]
__global__ __launch_bounds__(256)
void wvst_kernel(const float* __restrict__ Wv, float* __restrict__ wvsT)
{
    int idx = blockIdx.x * 256 + threadIdx.x;   // 65536 total
    int d = idx >> 10;
    int e = idx & 1023;
    float s = 0.f;
    #pragma unroll
    for (int h = 0; h < 16; ++h) s += Wv[(size_t)(h * 64 + d) * 1024 + e];
    wvsT[(size_t)e * 64 + d] = s;
}

// ---------------------------------------------------------------------------
// bf16 GEMM, m97-style: C[m][o] = sum_k A[m][k] * B[o][k]  (B^T layout)
// 128x128 tile, BK=32, 4 waves (2x2), 16x16x32 MFMA, global_load_lds width 16.
template<bool F32OUT>
__global__ __launch_bounds__(256)
void gemm_bt(const u16* __restrict__ A, const u16* __restrict__ Bw,
             void* __restrict__ Cv, const float* __restrict__ bias,
             int M, int N, int K)
{
    __shared__ u16 lsA[128 * 32];
    __shared__ u16 lsB[128 * 32];
    const int tid  = threadIdx.x;
    const int wave = tid >> 6;
    const int lane = tid & 63;
    const long row0 = (long)blockIdx.y * 128;
    const long col0 = (long)blockIdx.x * 128;
    const int wr = (wave >> 1) * 64;
    const int wc = (wave & 1) * 64;
    const int fr = lane & 15;
    const int k8 = (lane >> 4) * 8;

    f32x4 acc[4][4] = {};

    const int c0 = wave * 64 + lane;        // staging chunk, iter 0
    const int c1 = 256 + c0;                // staging chunk, iter 1

    for (int k0 = 0; k0 < K; k0 += 32) {
#ifdef HAVE_GLOAD_LDS
        gload_lds16(&A [(row0 + (c0 >> 2)) * K + k0 + (c0 & 3) * 8], &lsA[wave * 512]);
        gload_lds16(&A [(row0 + (c1 >> 2)) * K + k0 + (c1 & 3) * 8], &lsA[2048 + wave * 512]);
        gload_lds16(&Bw[(col0 + (c0 >> 2)) * K + k0 + (c0 & 3) * 8], &lsB[wave * 512]);
        gload_lds16(&Bw[(col0 + (c1 >> 2)) * K + k0 + (c1 & 3) * 8], &lsB[2048 + wave * 512]);
#else
        short8 ta0 = *(const short8*)&A [(row0 + (c0 >> 2)) * K + k0 + (c0 & 3) * 8];
        short8 ta1 = *(const short8*)&A [(row0 + (c1 >> 2)) * K + k0 + (c1 & 3) * 8];
        short8 tb0 = *(const short8*)&Bw[(col0 + (c0 >> 2)) * K + k0 + (c0 & 3) * 8];
        short8 tb1 = *(const short8*)&Bw[(col0 + (c1 >> 2)) * K + k0 + (c1 & 3) * 8];
        *(short8*)&lsA[(size_t)c0 * 8] = ta0;
        *(short8*)&lsA[(size_t)c1 * 8] = ta1;
        *(short8*)&lsB[(size_t)c0 * 8] = tb0;
        *(short8*)&lsB[(size_t)c1 * 8] = tb1;
#endif
        __syncthreads();
        short8 af[4], bf[4];
        #pragma unroll
        for (int m = 0; m < 4; ++m)
            af[m] = *(const short8*)&lsA[(wr + m * 16 + fr) * 32 + k8];
        #pragma unroll
        for (int n = 0; n < 4; ++n)
            bf[n] = *(const short8*)&lsB[(wc + n * 16 + fr) * 32 + k8];
        #pragma unroll
        for (int m = 0; m < 4; ++m)
            #pragma unroll
            for (int n = 0; n < 4; ++n)
                acc[m][n] = __builtin_amdgcn_mfma_f32_16x16x32_bf16(af[m], bf[n], acc[m][n], 0, 0, 0);
        __syncthreads();
    }

    const int orow = (lane >> 4) * 4;       // C/D: col=lane&15, row=(lane>>4)*4+j  [m89]
    #pragma unroll
    for (int m = 0; m < 4; ++m) {
        #pragma unroll
        for (int n = 0; n < 4; ++n) {
            long gr = row0 + wr + m * 16 + orow;
            long gc = col0 + wc + n * 16 + fr;
            #pragma unroll
            for (int j = 0; j < 4; ++j) {
                float v = acc[m][n][j];
                if (F32OUT) ((float*)Cv)[(gr + j) * N + gc] = v + bias[gc];
                else        ((u16*)  Cv)[(gr + j) * N + gc] = f2bf(v);
            }
        }
    }
}

// ---------------------------------------------------------------------------
// Vs[m][d] = sum_e x[m][e] * WvsT[e][d]   (m = n*4096+s), 8 rows per block
__global__ __launch_bounds__(256)
void vs_kernel(const u16* __restrict__ xb, const float* __restrict__ wvsT,
               float* __restrict__ Vs)
{
    __shared__ float xs[8][1024];
    const int t = threadIdx.x;
    const size_t r0 = (size_t)blockIdx.x * 8;
    for (int c = t; c < 1024; c += 256) {       // 8*1024 elems / 8 per chunk
        int r = c >> 7; int e = (c & 127) * 8;
        short8 v = *(const short8*)&xb[(r0 + r) * 1024 + e];
        #pragma unroll
        for (int j = 0; j < 8; ++j) xs[r][e + j] = bf2f((u16)v[j]);
    }
    __syncthreads();
    const int d  = t & 63;
    const int rq = (t >> 6) * 2;
    float a0 = 0.f, a1 = 0.f;
    for (int e = 0; e < 1024; ++e) {
        float w = wvsT[(size_t)e * 64 + d];
        a0 += w * xs[rq + 0][e];
        a1 += w * xs[rq + 1][e];
    }
    Vs[(r0 + rq + 0) * 64 + d] = a0;
    Vs[(r0 + rq + 1) * 64 + d] = a1;
}

// energy[site][i*16+j] = sum_d Q[site][i*64+d] * K[site][j*64+d], 1 wave/site
__global__ __launch_bounds__(256)
void energy_kernel(const u16* __restrict__ Qb, const u16* __restrict__ Kb,
                   float* __restrict__ E)
{
    const int lane = threadIdx.x & 63;
    const size_t site = (size_t)blockIdx.x * 4 + (threadIdx.x >> 6);
    const size_t base = site * 1024;
    const int hh = lane & 15;
    const int kg = (lane >> 4) * 8;
    short8 a0 = *(const short8*)&Qb[base + hh * 64 + kg];
    short8 a1 = *(const short8*)&Qb[base + hh * 64 + 32 + kg];
    short8 b0 = *(const short8*)&Kb[base + hh * 64 + kg];
    short8 b1 = *(const short8*)&Kb[base + hh * 64 + 32 + kg];
    f32x4 acc = {};
    acc = __builtin_amdgcn_mfma_f32_16x16x32_bf16(a0, b0, acc, 0, 0, 0);
    acc = __builtin_amdgcn_mfma_f32_16x16x32_bf16(a1, b1, acc, 0, 0, 0);
    float* out = E + site * 256;
    const int ib = (lane >> 4) * 4;
    #pragma unroll
    for (int r = 0; r < 4; ++r)
        out[(ib + r) * 16 + hh] = acc[r];       // row=i, col=j
}

// per-(n,i,j) softmax stats over s, chunked (64 chunk-blocks of 256 sites)
__global__ __launch_bounds__(256)
void stats_pmax(const float* __restrict__ E, float* __restrict__ pmax)
{
    const int b = blockIdx.x, p = threadIdx.x;
    const float* e = E + (size_t)b * 65536 + p;
    float m = -3.4e38f;
    for (int s = 0; s < 256; ++s) m = fmaxf(m, e[(size_t)s * 256]);
    pmax[b * 256 + p] = m;
}
__global__ __launch_bounds__(256)
void stats_gmax(const float* __restrict__ pmax, float* __restrict__ gmax)
{
    const int n = blockIdx.x, p = threadIdx.x;
    float m = -3.4e38f;
    for (int c = 0; c < 16; ++c) m = fmaxf(m, pmax[(n * 16 + c) * 256 + p]);
    gmax[n * 256 + p] = m;
}
__global__ __launch_bounds__(256)
void stats_psum(const float* __restrict__ E, const float* __restrict__ gmax,
                float* __restrict__ psum)
{
    const int b = blockIdx.x, p = threadIdx.x;
    const float m = gmax[(b >> 4) * 256 + p];
    const float* e = E + (size_t)b * 65536 + p;
    float z = 0.f;
    for (int s = 0; s < 256; ++s) z += __expf((e[(size_t)s * 256] - m) * 0.125f);
    psum[b * 256 + p] = z;
}
__global__ __launch_bounds__(256)
void stats_invz(const float* __restrict__ psum, float* __restrict__ invZ)
{
    const int n = blockIdx.x, p = threadIdx.x;
    float z = 0.f;
    for (int c = 0; c < 16; ++c) z += psum[(n * 16 + c) * 256 + p];
    invZ[n * 256 + p] = 1.0f / z;
}

// A[srow][i] = sum_j exp((E[srow][i*16+j]-m)/8) * invZ
__global__ __launch_bounds__(256)
void a_kernel(const float* __restrict__ E, const float* __restrict__ gmax,
              const float* __restrict__ invZ, float* __restrict__ A)
{
    __shared__ float sm[256], sz[256];
    const int b = blockIdx.x, t = threadIdx.x;
    const int n = b >> 8;
    sm[t] = gmax[n * 256 + t];
    sz[t] = invZ[n * 256 + t];
    __syncthreads();
    const int sl = t >> 4, i = t & 15;
    const size_t srow = (size_t)n * 4096 + (size_t)(b & 255) * 16 + sl;
    const float* e = E + srow * 256 + i * 16;
    float a = 0.f;
    #pragma unroll
    for (int j = 0; j < 16; ++j)
        a += __expf((e[j] - sm[i * 16 + j]) * 0.125f) * sz[i * 16 + j];
    A[srow * 16 + i] = a;
}

// Z2[n][s2][e2] = bf16( A[n][i][s] * Vs[n][s][d] ),  i=s2>>8, s=(s2&255)*16+e2/64, d=e2&63
__global__ __launch_bounds__(256)
void z2_kernel(const float* __restrict__ A, const float* __restrict__ Vs,
               u16* __restrict__ Z2)
{
    const size_t idx = ((size_t)blockIdx.x * 256 + threadIdx.x) * 8;
    const int e2 = (int)(idx & 1023);
    const size_t row = idx >> 10;               // n*4096 + s2
    const int s2 = (int)(row & 4095);
    const int n  = (int)(row >> 12);
    const int i  = s2 >> 8;
    const int s  = ((s2 & 255) << 4) + (e2 >> 6);
    const int d  = e2 & 63;
    const size_t srow = (size_t)n * 4096 + s;
    const float a = A[srow * 16 + i];
    f32x4 v0 = *(const f32x4*)&Vs[srow * 64 + d];
    f32x4 v1 = *(const f32x4*)&Vs[srow * 64 + d + 4];
    u16x8 o;
    o[0]=f2bf(a*v0[0]); o[1]=f2bf(a*v0[1]); o[2]=f2bf(a*v0[2]); o[3]=f2bf(a*v0[3]);
    o[4]=f2bf(a*v1[0]); o[5]=f2bf(a*v1[1]); o[6]=f2bf(a*v1[2]); o[7]=f2bf(a*v1[3]);
    *(u16x8*)&Z2[idx] = o;
}

// ---------------------------------------------------------------------------
extern "C" void kernel_launch(void* const* d_in, const int* in_sizes, int n_in,
                              void* d_out, int out_size, void* d_ws, size_t ws_size,
                              hipStream_t stream)
{
    const float* x  = (const float*)d_in[0];
    const float* Wq = (const float*)d_in[1];
    const float* Wk = (const float*)d_in[2];
    const float* Wv = (const float*)d_in[3];
    const float* Wo = (const float*)d_in[4];
    const float* bo = (const float*)d_in[5];
    float* out = (float*)d_out;
    char* ws = (char*)d_ws;

    u16*   xb   = (u16*)  (ws + OFF_XB);
    float* En   = (float*)(ws + OFF_EN);    // aliases xb (xb dead by then)
    u16*   Qb   = (u16*)  (ws + OFF_QB);
    u16*   Z2   = (u16*)  (ws + OFF_QB);    // aliases Qb (Qb dead by then)
    u16*   Kb   = (u16*)  (ws + OFF_KB);
    u16*   Wqb  = (u16*)  (ws + OFF_WQB);
    u16*   Wkb  = (u16*)  (ws + OFF_WKB);
    u16*   Wob  = (u16*)  (ws + OFF_WOB);
    float* WvsT = (float*)(ws + OFF_WVST);
    float* Vs   = (float*)(ws + OFF_VS);
    float* pmax = (float*)(ws + OFF_PMAX);
    float* psum = (float*)(ws + OFF_PSUM);
    float* gmax = (float*)(ws + OFF_GMAX);
    float* invZ = (float*)(ws + OFF_INVZ);
    float* Ab   = (float*)(ws + OFF_A);

    // 1. casts + head-reduced Wv
    cvt_kernel <<<9728, 256, 0, stream>>>(x, Wq, Wk, Wo, xb, Wqb, Wkb, Wob);
    wvst_kernel<<<256,  256, 0, stream>>>(Wv, WvsT);

    // 2. Q, K projections (bf16 MFMA GEMM), Vs (head-summed V)
    gemm_bt<false><<<dim3(8, 128), 256, 0, stream>>>(xb, Wqb, (void*)Qb, nullptr, 16384, 1024, 1024);
    gemm_bt<false><<<dim3(8, 128), 256, 0, stream>>>(xb, Wkb, (void*)Kb, nullptr, 16384, 1024, 1024);
    vs_kernel<<<2048, 256, 0, stream>>>(xb, WvsT, Vs);

    // 3. per-site 16x16 head-Gram energy (overwrites xb region)
    energy_kernel<<<4096, 256, 0, stream>>>(Qb, Kb, En);

    // 4. softmax-over-S stats, A, Z2
    stats_pmax<<<64, 256, 0, stream>>>(En, pmax);
    stats_gmax<<<4,  256, 0, stream>>>(pmax, gmax);
    stats_psum<<<64, 256, 0, stream>>>(En, gmax, psum);
    stats_invz<<<4,  256, 0, stream>>>(psum, invZ);
    a_kernel  <<<1024, 256, 0, stream>>>(En, gmax, invZ, Ab);
    z2_kernel <<<8192, 256, 0, stream>>>(Ab, Vs, Z2);

    // 5. output projection + bias -> fp32 d_out
    gemm_bt<true><<<dim3(8, 128), 256, 0, stream>>>(Z2, Wob, (void*)out, bo, 16384, 1024, 1024);
}

// Round 2
// 274.469 us; speedup vs baseline: 1.3161x; 1.3161x over previous
//
#include <hip/hip_runtime.h>
#include <stdint.h>

typedef unsigned short u16;
typedef unsigned int   u32;
typedef __attribute__((ext_vector_type(8))) short short8;
typedef __attribute__((ext_vector_type(4))) float f32x4;
typedef __attribute__((ext_vector_type(8))) u16   u16x8;

// Problem constants: N=4, S=4096, E=1024, H=16, D=64
static constexpr size_t NX = (size_t)4 * 4096 * 1024;   // 16,777,216 x elems
static constexpr size_t NW = (size_t)1024 * 1024;       // 1,048,576 weight elems

// Workspace layout (bytes). energy aliases xb (xb dead after QK/Vs GEMMs).
// Z2 aliases Qb (Qb dead after energy kernel). pmax/psum alias the A region
// (consumed by stats_comb before a_kernel writes A). Peak ~107 MB.
static constexpr size_t OFF_XB   = 0;                   // 33,554,432  bf16 x
static constexpr size_t OFF_EN   = 0;                   // 16,777,216  f32 energy [16384][256]
static constexpr size_t OFF_QB   = 33554432;            // 33,554,432  bf16 Q  (later Z2)
static constexpr size_t OFF_KB   = 67108864;            // 33,554,432  bf16 K
static constexpr size_t OFF_WQB  = 100663296;           // 2,097,152
static constexpr size_t OFF_WKB  = 102760448;           // 2,097,152
static constexpr size_t OFF_WOB  = 104857600;           // 2,097,152
static constexpr size_t OFF_WVST = 106954752;           // 131,072  bf16 Bvs [64][1024]
static constexpr size_t OFF_VS   = 107216896;           // 4,194,304 f32 [16384][64]
static constexpr size_t OFF_GMAX = 111411200;           // 4,096
static constexpr size_t OFF_INVZ = 111415296;           // 4,096
static constexpr size_t OFF_A    = 111419392;           // 1,048,576 f32 [16384][16]
// pmax/psum (256KB each) alias OFF_A (dead before a_kernel writes A)

static __device__ __forceinline__ u16 f2bf(float f) {
    u32 u = __builtin_bit_cast(u32, f);
    u += 0x7fffu + ((u >> 16) & 1u);        // RNE
    return (u16)(u >> 16);
}
static __device__ __forceinline__ float bf2f(u16 v) {
    u32 u = ((u32)v) << 16;
    return __builtin_bit_cast(float, u);
}

#if __has_builtin(__builtin_amdgcn_global_load_lds)
#define HAVE_GLOAD_LDS 1
static __device__ __forceinline__ void gload_lds16(const void* g, void* l) {
    __builtin_amdgcn_global_load_lds(
        (__attribute__((address_space(1))) void*)(uintptr_t)g,
        (__attribute__((address_space(3))) void*)(uintptr_t)l,
        16, 0, 0);
}
#endif

// ---------------------------------------------------------------------------
// fused fp32 -> bf16 conversion for x, Wq, Wk, Wo
__global__ __launch_bounds__(256)
void cvt_kernel(const float* __restrict__ x, const float* __restrict__ wq,
                const float* __restrict__ wk, const float* __restrict__ wo,
                u16* __restrict__ xb, u16* __restrict__ wqb,
                u16* __restrict__ wkb, u16* __restrict__ wob)
{
    size_t i = ((size_t)blockIdx.x * 256 + threadIdx.x) * 8;
    const float* s; u16* dst; size_t o;
    if (i < NX) { s = x; dst = xb; o = i; }
    else {
        size_t r = i - NX;
        int w = (int)(r >> 20);             // NW = 2^20
        o = r & (NW - 1);
        s   = (w == 0) ? wq  : (w == 1) ? wk  : wo;
        dst = (w == 0) ? wqb : (w == 1) ? wkb : wob;
    }
    f32x4 a = *(const f32x4*)&s[o];
    f32x4 c = *(const f32x4*)&s[o + 4];
    u16x8 v;
    v[0]=f2bf(a[0]); v[1]=f2bf(a[1]); v[2]=f2bf(a[2]); v[3]=f2bf(a[3]);
    v[4]=f2bf(c[0]); v[5]=f2bf(c[1]); v[6]=f2bf(c[2]); v[7]=f2bf(c[3]);
    *(u16x8*)&dst[o] = v;
}

// Bvs[d][e] = bf16( sum_h Wv[(h*64+d)*1024 + e] )   (B^T layout for gemm_vs)
__global__ __launch_bounds__(256)
void wvst_kernel(const float* __restrict__ Wv, u16* __restrict__ Bvs)
{
    int idx = blockIdx.x * 256 + threadIdx.x;   // 65536 total
    int d = idx >> 10;
    int e = idx & 1023;
    float s = 0.f;
    #pragma unroll
    for (int h = 0; h < 16; ++h) s += Wv[(size_t)(h * 64 + d) * 1024 + e];
    Bvs[(size_t)d * 1024 + e] = f2bf(s);
}

// ---------------------------------------------------------------------------
// bf16 GEMM, m97-style: C[m][o] = sum_k A[m][k] * B[o][k]  (B^T layout)
// 128x128 tile, BK=32, 4 waves (2x2), 16x16x32 MFMA, global_load_lds width 16.
template<bool F32OUT>
__global__ __launch_bounds__(256)
void gemm_bt(const u16* __restrict__ A, const u16* __restrict__ Bw,
             void* __restrict__ Cv, const float* __restrict__ bias,
             int M, int N, int K)
{
    __shared__ u16 lsA[128 * 32];
    __shared__ u16 lsB[128 * 32];
    const int tid  = threadIdx.x;
    const int wave = tid >> 6;
    const int lane = tid & 63;
    const long row0 = (long)blockIdx.y * 128;
    const long col0 = (long)blockIdx.x * 128;
    const int wr = (wave >> 1) * 64;
    const int wc = (wave & 1) * 64;
    const int fr = lane & 15;
    const int k8 = (lane >> 4) * 8;

    f32x4 acc[4][4] = {};

    const int c0 = wave * 64 + lane;        // staging chunk, iter 0
    const int c1 = 256 + c0;                // staging chunk, iter 1

    for (int k0 = 0; k0 < K; k0 += 32) {
#ifdef HAVE_GLOAD_LDS
        gload_lds16(&A [(row0 + (c0 >> 2)) * K + k0 + (c0 & 3) * 8], &lsA[wave * 512]);
        gload_lds16(&A [(row0 + (c1 >> 2)) * K + k0 + (c1 & 3) * 8], &lsA[2048 + wave * 512]);
        gload_lds16(&Bw[(col0 + (c0 >> 2)) * K + k0 + (c0 & 3) * 8], &lsB[wave * 512]);
        gload_lds16(&Bw[(col0 + (c1 >> 2)) * K + k0 + (c1 & 3) * 8], &lsB[2048 + wave * 512]);
#else
        short8 ta0 = *(const short8*)&A [(row0 + (c0 >> 2)) * K + k0 + (c0 & 3) * 8];
        short8 ta1 = *(const short8*)&A [(row0 + (c1 >> 2)) * K + k0 + (c1 & 3) * 8];
        short8 tb0 = *(const short8*)&Bw[(col0 + (c0 >> 2)) * K + k0 + (c0 & 3) * 8];
        short8 tb1 = *(const short8*)&Bw[(col0 + (c1 >> 2)) * K + k0 + (c1 & 3) * 8];
        *(short8*)&lsA[(size_t)c0 * 8] = ta0;
        *(short8*)&lsA[(size_t)c1 * 8] = ta1;
        *(short8*)&lsB[(size_t)c0 * 8] = tb0;
        *(short8*)&lsB[(size_t)c1 * 8] = tb1;
#endif
        __syncthreads();
        short8 af[4], bf[4];
        #pragma unroll
        for (int m = 0; m < 4; ++m)
            af[m] = *(const short8*)&lsA[(wr + m * 16 + fr) * 32 + k8];
        #pragma unroll
        for (int n = 0; n < 4; ++n)
            bf[n] = *(const short8*)&lsB[(wc + n * 16 + fr) * 32 + k8];
        #pragma unroll
        for (int m = 0; m < 4; ++m)
            #pragma unroll
            for (int n = 0; n < 4; ++n)
                acc[m][n] = __builtin_amdgcn_mfma_f32_16x16x32_bf16(af[m], bf[n], acc[m][n], 0, 0, 0);
        __syncthreads();
    }

    const int orow = (lane >> 4) * 4;       // C/D: col=lane&15, row=(lane>>4)*4+j  [m89]
    #pragma unroll
    for (int m = 0; m < 4; ++m) {
        #pragma unroll
        for (int n = 0; n < 4; ++n) {
            long gr = row0 + wr + m * 16 + orow;
            long gc = col0 + wc + n * 16 + fr;
            #pragma unroll
            for (int j = 0; j < 4; ++j) {
                float v = acc[m][n][j];
                if (F32OUT) ((float*)Cv)[(gr + j) * N + gc] = v + bias[gc];
                else        ((u16*)  Cv)[(gr + j) * N + gc] = f2bf(v);
            }
        }
    }
}

// ---------------------------------------------------------------------------
// Vs = xb @ Bvs^T : M=16384, N=64, K=1024. 64x64 tile, 4 waves (2x2 of 32x32),
// MFMA 16x16x32, f32 output. Grid = 256 blocks (1 per CU).
__global__ __launch_bounds__(256)
void gemm_vs(const u16* __restrict__ A, const u16* __restrict__ Bw,
             float* __restrict__ C)
{
    __shared__ u16 lsA[64 * 32];
    __shared__ u16 lsB[64 * 32];
    const int tid  = threadIdx.x;
    const int wave = tid >> 6;
    const int lane = tid & 63;
    const long row0 = (long)blockIdx.x * 64;
    const int wr = (wave >> 1) * 32;
    const int wc = (wave & 1) * 32;
    const int fr = lane & 15;
    const int k8 = (lane >> 4) * 8;

    f32x4 acc[2][2] = {};
    const int c0 = tid;                     // one 8-elem chunk per thread

    for (int k0 = 0; k0 < 1024; k0 += 32) {
#ifdef HAVE_GLOAD_LDS
        gload_lds16(&A [(row0 + (c0 >> 2)) * 1024 + k0 + (c0 & 3) * 8], &lsA[wave * 512]);
        gload_lds16(&Bw[((size_t)(c0 >> 2)) * 1024 + k0 + (c0 & 3) * 8], &lsB[wave * 512]);
#else
        short8 ta = *(const short8*)&A [(row0 + (c0 >> 2)) * 1024 + k0 + (c0 & 3) * 8];
        short8 tb = *(const short8*)&Bw[((size_t)(c0 >> 2)) * 1024 + k0 + (c0 & 3) * 8];
        *(short8*)&lsA[(size_t)c0 * 8] = ta;
        *(short8*)&lsB[(size_t)c0 * 8] = tb;
#endif
        __syncthreads();
        short8 af[2], bf[2];
        #pragma unroll
        for (int m = 0; m < 2; ++m)
            af[m] = *(const short8*)&lsA[(wr + m * 16 + fr) * 32 + k8];
        #pragma unroll
        for (int n = 0; n < 2; ++n)
            bf[n] = *(const short8*)&lsB[(wc + n * 16 + fr) * 32 + k8];
        #pragma unroll
        for (int m = 0; m < 2; ++m)
            #pragma unroll
            for (int n = 0; n < 2; ++n)
                acc[m][n] = __builtin_amdgcn_mfma_f32_16x16x32_bf16(af[m], bf[n], acc[m][n], 0, 0, 0);
        __syncthreads();
    }

    const int orow = (lane >> 4) * 4;
    #pragma unroll
    for (int m = 0; m < 2; ++m) {
        #pragma unroll
        for (int n = 0; n < 2; ++n) {
            long gr = row0 + wr + m * 16 + orow;
            int  gc = wc + n * 16 + fr;
            #pragma unroll
            for (int j = 0; j < 4; ++j)
                C[(gr + j) * 64 + gc] = acc[m][n][j];
        }
    }
}

// energy[site][i*16+j] = sum_d Q[site][i*64+d] * K[site][j*64+d], 1 wave/site
__global__ __launch_bounds__(256)
void energy_kernel(const u16* __restrict__ Qb, const u16* __restrict__ Kb,
                   float* __restrict__ E)
{
    const int lane = threadIdx.x & 63;
    const size_t site = (size_t)blockIdx.x * 4 + (threadIdx.x >> 6);
    const size_t base = site * 1024;
    const int hh = lane & 15;
    const int kg = (lane >> 4) * 8;
    short8 a0 = *(const short8*)&Qb[base + hh * 64 + kg];
    short8 a1 = *(const short8*)&Qb[base + hh * 64 + 32 + kg];
    short8 b0 = *(const short8*)&Kb[base + hh * 64 + kg];
    short8 b1 = *(const short8*)&Kb[base + hh * 64 + 32 + kg];
    f32x4 acc = {};
    acc = __builtin_amdgcn_mfma_f32_16x16x32_bf16(a0, b0, acc, 0, 0, 0);
    acc = __builtin_amdgcn_mfma_f32_16x16x32_bf16(a1, b1, acc, 0, 0, 0);
    float* out = E + site * 256;
    const int ib = (lane >> 4) * 4;
    #pragma unroll
    for (int r = 0; r < 4; ++r)
        out[(ib + r) * 16 + hh] = acc[r];       // row=i, col=j
}

// ---------------------------------------------------------------------------
// single-pass chunked softmax stats over s: 256 blocks x 64-site chunks.
// Each thread p in block b=(n*64+chunk): local max + local sum-exp.
__global__ __launch_bounds__(256)
void stats_part(const float* __restrict__ E, float* __restrict__ pmax,
                float* __restrict__ psum)
{
    const int b = blockIdx.x, p = threadIdx.x;
    const float* e = E + (size_t)b * 64 * 256 + p;
    float m = -3.4e38f;
    float buf[64];
    #pragma unroll 8
    for (int s = 0; s < 64; ++s) {
        float v = e[(size_t)s * 256];
        buf[s] = v;
        m = fmaxf(m, v);
    }
    float z = 0.f;
    #pragma unroll 8
    for (int s = 0; s < 64; ++s) z += __expf((buf[s] - m) * 0.125f);
    pmax[b * 256 + p] = m;
    psum[b * 256 + p] = z;
}
__global__ __launch_bounds__(256)
void stats_comb(const float* __restrict__ pmax, const float* __restrict__ psum,
                float* __restrict__ gmax, float* __restrict__ invZ)
{
    const int n = blockIdx.x, p = threadIdx.x;
    float m = -3.4e38f;
    #pragma unroll 8
    for (int c = 0; c < 64; ++c) m = fmaxf(m, pmax[(n * 64 + c) * 256 + p]);
    float z = 0.f;
    #pragma unroll 8
    for (int c = 0; c < 64; ++c)
        z += psum[(n * 64 + c) * 256 + p] * __expf((pmax[(n * 64 + c) * 256 + p] - m) * 0.125f);
    gmax[n * 256 + p] = m;
    invZ[n * 256 + p] = 1.0f / z;
}

// A[srow][i] = sum_j exp((E[srow][i*16+j]-m)/8) * invZ
__global__ __launch_bounds__(256)
void a_kernel(const float* __restrict__ E, const float* __restrict__ gmax,
              const float* __restrict__ invZ, float* __restrict__ A)
{
    __shared__ float sm[256], sz[256];
    const int b = blockIdx.x, t = threadIdx.x;
    const int n = b >> 8;
    sm[t] = gmax[n * 256 + t];
    sz[t] = invZ[n * 256 + t];
    __syncthreads();
    const int sl = t >> 4, i = t & 15;
    const size_t srow = (size_t)n * 4096 + (size_t)(b & 255) * 16 + sl;
    const float* e = E + srow * 256 + i * 16;
    float a = 0.f;
    #pragma unroll
    for (int j = 0; j < 16; ++j)
        a += __expf((e[j] - sm[i * 16 + j]) * 0.125f) * sz[i * 16 + j];
    A[srow * 16 + i] = a;
}

// Z2[n][s2][e2] = bf16( A[n][i][s] * Vs[n][s][d] ),  i=s2>>8, s=(s2&255)*16+e2/64, d=e2&63
__global__ __launch_bounds__(256)
void z2_kernel(const float* __restrict__ A, const float* __restrict__ Vs,
               u16* __restrict__ Z2)
{
    const size_t idx = ((size_t)blockIdx.x * 256 + threadIdx.x) * 8;
    const int e2 = (int)(idx & 1023);
    const size_t row = idx >> 10;               // n*4096 + s2
    const int s2 = (int)(row & 4095);
    const int n  = (int)(row >> 12);
    const int i  = s2 >> 8;
    const int s  = ((s2 & 255) << 4) + (e2 >> 6);
    const int d  = e2 & 63;
    const size_t srow = (size_t)n * 4096 + s;
    const float a = A[srow * 16 + i];
    f32x4 v0 = *(const f32x4*)&Vs[srow * 64 + d];
    f32x4 v1 = *(const f32x4*)&Vs[srow * 64 + d + 4];
    u16x8 o;
    o[0]=f2bf(a*v0[0]); o[1]=f2bf(a*v0[1]); o[2]=f2bf(a*v0[2]); o[3]=f2bf(a*v0[3]);
    o[4]=f2bf(a*v1[0]); o[5]=f2bf(a*v1[1]); o[6]=f2bf(a*v1[2]); o[7]=f2bf(a*v1[3]);
    *(u16x8*)&Z2[idx] = o;
}

// ---------------------------------------------------------------------------
extern "C" void kernel_launch(void* const* d_in, const int* in_sizes, int n_in,
                              void* d_out, int out_size, void* d_ws, size_t ws_size,
                              hipStream_t stream)
{
    const float* x  = (const float*)d_in[0];
    const float* Wq = (const float*)d_in[1];
    const float* Wk = (const float*)d_in[2];
    const float* Wv = (const float*)d_in[3];
    const float* Wo = (const float*)d_in[4];
    const float* bo = (const float*)d_in[5];
    float* out = (float*)d_out;
    char* ws = (char*)d_ws;

    u16*   xb   = (u16*)  (ws + OFF_XB);
    float* En   = (float*)(ws + OFF_EN);    // aliases xb (xb dead by then)
    u16*   Qb   = (u16*)  (ws + OFF_QB);
    u16*   Z2   = (u16*)  (ws + OFF_QB);    // aliases Qb (Qb dead by then)
    u16*   Kb   = (u16*)  (ws + OFF_KB);
    u16*   Wqb  = (u16*)  (ws + OFF_WQB);
    u16*   Wkb  = (u16*)  (ws + OFF_WKB);
    u16*   Wob  = (u16*)  (ws + OFF_WOB);
    u16*   Bvs  = (u16*)  (ws + OFF_WVST);
    float* Vs   = (float*)(ws + OFF_VS);
    float* gmax = (float*)(ws + OFF_GMAX);
    float* invZ = (float*)(ws + OFF_INVZ);
    float* Ab   = (float*)(ws + OFF_A);
    float* pmax = (float*)(ws + OFF_A);             // alias: dead before A written
    float* psum = (float*)(ws + OFF_A + 262144);    // alias: dead before A written

    // 1. casts + head-reduced bf16 Wv (B^T layout)
    cvt_kernel <<<9728, 256, 0, stream>>>(x, Wq, Wk, Wo, xb, Wqb, Wkb, Wob);
    wvst_kernel<<<256,  256, 0, stream>>>(Wv, Bvs);

    // 2. Q, K projections + head-summed V (all bf16 MFMA GEMMs)
    gemm_bt<false><<<dim3(8, 128), 256, 0, stream>>>(xb, Wqb, (void*)Qb, nullptr, 16384, 1024, 1024);
    gemm_bt<false><<<dim3(8, 128), 256, 0, stream>>>(xb, Wkb, (void*)Kb, nullptr, 16384, 1024, 1024);
    gemm_vs<<<256, 256, 0, stream>>>(xb, Bvs, Vs);

    // 3. per-site 16x16 head-Gram energy (overwrites xb region)
    energy_kernel<<<4096, 256, 0, stream>>>(Qb, Kb, En);

    // 4. softmax-over-S stats (single online pass), A, Z2
    stats_part<<<256, 256, 0, stream>>>(En, pmax, psum);
    stats_comb<<<4,   256, 0, stream>>>(pmax, psum, gmax, invZ);
    a_kernel  <<<1024, 256, 0, stream>>>(En, gmax, invZ, Ab);
    z2_kernel <<<8192, 256, 0, stream>>>(Ab, Vs, Z2);

    // 5. output projection + bias -> fp32 d_out
    gemm_bt<true><<<dim3(8, 128), 256, 0, stream>>>(Z2, Wob, (void*)out, bo, 16384, 1024, 1024);
}

// Round 3
// 221.248 us; speedup vs baseline: 1.6327x; 1.2405x over previous
//
#include <hip/hip_runtime.h>
#include <stdint.h>

typedef unsigned short u16;
typedef unsigned int   u32;
typedef __attribute__((ext_vector_type(8))) short short8;
typedef __attribute__((ext_vector_type(4))) float f32x4;
typedef __attribute__((ext_vector_type(8))) u16   u16x8;

// Problem constants: N=4, S=4096, E=1024, H=16, D=64
static constexpr size_t NX = (size_t)4 * 4096 * 1024;   // 16,777,216 x elems
static constexpr size_t NW = (size_t)1024 * 1024;       // 1,048,576 weight elems

// Workspace layout (bytes). energy aliases xb (xb dead after QK/Vs GEMMs).
// Z2 aliases QKb (QKb dead after energy kernel). pmax/psum alias the A region
// (consumed by stats_comb before a_kernel writes A). Peak ~113 MB.
static constexpr size_t OFF_XB   = 0;                   // 33,554,432  bf16 x
static constexpr size_t OFF_EN   = 0;                   // 16,777,216  f32 energy [16384][256]
static constexpr size_t OFF_QK   = 33554432;            // 67,108,864  bf16 QK [16384][2048] (later Z2)
static constexpr size_t OFF_WQB  = 100663296;           // 2,097,152  (Wkb contiguous after)
static constexpr size_t OFF_WKB  = 102760448;           // 2,097,152
static constexpr size_t OFF_WOB  = 104857600;           // 2,097,152
static constexpr size_t OFF_WVST = 106954752;           // 131,072  bf16 Bvs [64][1024]
static constexpr size_t OFF_VS   = 107216896;           // 4,194,304 f32 [16384][64]
static constexpr size_t OFF_GMAX = 111411200;           // 4,096
static constexpr size_t OFF_INVZ = 111415296;           // 4,096
static constexpr size_t OFF_A    = 111419392;           // 1,048,576 f32 [16384][16]
// pmax/psum (256KB each) alias OFF_A (dead before a_kernel writes A)

static __device__ __forceinline__ u16 f2bf(float f) {
    u32 u = __builtin_bit_cast(u32, f);
    u += 0x7fffu + ((u >> 16) & 1u);        // RNE
    return (u16)(u >> 16);
}
static __device__ __forceinline__ float bf2f(u16 v) {
    u32 u = ((u32)v) << 16;
    return __builtin_bit_cast(float, u);
}

#if __has_builtin(__builtin_amdgcn_global_load_lds)
#define HAVE_GLOAD_LDS 1
static __device__ __forceinline__ void gload_lds16(const void* g, void* l) {
    __builtin_amdgcn_global_load_lds(
        (__attribute__((address_space(1))) void*)(uintptr_t)g,
        (__attribute__((address_space(3))) void*)(uintptr_t)l,
        16, 0, 0);
}
#endif

// ---------------------------------------------------------------------------
// fused fp32 -> bf16 conversion for x, Wq, Wk, Wo
__global__ __launch_bounds__(256)
void cvt_kernel(const float* __restrict__ x, const float* __restrict__ wq,
                const float* __restrict__ wk, const float* __restrict__ wo,
                u16* __restrict__ xb, u16* __restrict__ wqb,
                u16* __restrict__ wkb, u16* __restrict__ wob)
{
    size_t i = ((size_t)blockIdx.x * 256 + threadIdx.x) * 8;
    const float* s; u16* dst; size_t o;
    if (i < NX) { s = x; dst = xb; o = i; }
    else {
        size_t r = i - NX;
        int w = (int)(r >> 20);             // NW = 2^20
        o = r & (NW - 1);
        s   = (w == 0) ? wq  : (w == 1) ? wk  : wo;
        dst = (w == 0) ? wqb : (w == 1) ? wkb : wob;
    }
    f32x4 a = *(const f32x4*)&s[o];
    f32x4 c = *(const f32x4*)&s[o + 4];
    u16x8 v;
    v[0]=f2bf(a[0]); v[1]=f2bf(a[1]); v[2]=f2bf(a[2]); v[3]=f2bf(a[3]);
    v[4]=f2bf(c[0]); v[5]=f2bf(c[1]); v[6]=f2bf(c[2]); v[7]=f2bf(c[3]);
    *(u16x8*)&dst[o] = v;
}

// Bvs[d][e] = bf16( sum_h Wv[(h*64+d)*1024 + e] )   (B^T layout for gemm_vs)
__global__ __launch_bounds__(256)
void wvst_kernel(const float* __restrict__ Wv, u16* __restrict__ Bvs)
{
    int idx = blockIdx.x * 256 + threadIdx.x;   // 65536 total
    int d = idx >> 10;
    int e = idx & 1023;
    float s = 0.f;
    #pragma unroll
    for (int h = 0; h < 16; ++h) s += Wv[(size_t)(h * 64 + d) * 1024 + e];
    Bvs[(size_t)d * 1024 + e] = f2bf(s);
}

// ---------------------------------------------------------------------------
// bf16 GEMM: C[m][o] = sum_k A[m][k] * B[o][k]  (B^T layout)
// 128x128 tile, BK=32, 4 waves (2x2), 16x16x32 MFMA.
// T3 2-phase double-buffer + T2 granule XOR swizzle + T1 XCD swizzle.
// LDS granule = 16B (8 bf16). Tile granule (r, g), g in 0..3.
// Swizzle (both-sides involution, rule #21): linear LDS dest; SOURCE fetches
// granule g^((r>>1)&3); READ of (r,g) uses LDS granule g^((r>>1)&3).
template<bool F32OUT>
__global__ __launch_bounds__(256)
void gemm_bt(const u16* __restrict__ A, const u16* __restrict__ Bw,
             void* __restrict__ Cv, const float* __restrict__ bias,
             int M, int N, int K, int lognbx)
{
    __shared__ u16 lsA[2][128 * 32];
    __shared__ u16 lsB[2][128 * 32];
    const int tid  = threadIdx.x;
    const int wave = tid >> 6;
    const int lane = tid & 63;

    // XCD-aware bijective swizzle (gridDim.x % 8 == 0 guaranteed by launch)
    const int nwg = gridDim.x;
    const int swz = ((int)blockIdx.x & 7) * (nwg >> 3) + ((int)blockIdx.x >> 3);
    const long col0 = (long)(swz & ((1 << lognbx) - 1)) * 128;
    const long row0 = (long)(swz >> lognbx) * 128;

    const int wr = (wave >> 1) * 64;
    const int wc = (wave & 1) * 64;
    const int fr = lane & 15;
    const int gsw = (((lane >> 4) ^ ((fr >> 1) & 3))) * 8;  // swizzled read granule*8

    f32x4 acc[4][4] = {};

    // staging: 512 granule-chunks per tile, 2 per thread
    const int c0 = wave * 64 + lane;
    const int c1 = 256 + c0;
    const int gs = ((lane & 3) ^ ((lane >> 3) & 3)) * 8;    // swizzled source granule*8
    const u16* pa0 = &A [(row0 + (c0 >> 2)) * K + gs];
    const u16* pa1 = &A [(row0 + (c1 >> 2)) * K + gs];
    const u16* pb0 = &Bw[(col0 + (c0 >> 2)) * K + gs];
    const u16* pb1 = &Bw[(col0 + (c1 >> 2)) * K + gs];

    auto STAGE = [&](int buf, int k0) {
#ifdef HAVE_GLOAD_LDS
        gload_lds16(pa0 + k0, &lsA[buf][wave * 512]);
        gload_lds16(pa1 + k0, &lsA[buf][2048 + wave * 512]);
        gload_lds16(pb0 + k0, &lsB[buf][wave * 512]);
        gload_lds16(pb1 + k0, &lsB[buf][2048 + wave * 512]);
#else
        *(short8*)&lsA[buf][(size_t)c0 * 8] = *(const short8*)(pa0 + k0);
        *(short8*)&lsA[buf][(size_t)c1 * 8] = *(const short8*)(pa1 + k0);
        *(short8*)&lsB[buf][(size_t)c0 * 8] = *(const short8*)(pb0 + k0);
        *(short8*)&lsB[buf][(size_t)c1 * 8] = *(const short8*)(pb1 + k0);
#endif
    };

    STAGE(0, 0);
    __syncthreads();                        // drains vmcnt(0): tile 0 resident

    const int nt = K >> 5;
    for (int t = 0; t < nt; ++t) {
        const int cur = t & 1;
        if (t + 1 < nt) STAGE(cur ^ 1, (t + 1) << 5);   // prefetch next tile
        short8 af[4], bf[4];
        #pragma unroll
        for (int m = 0; m < 4; ++m)
            af[m] = *(const short8*)&lsA[cur][(wr + m * 16 + fr) * 32 + gsw];
        #pragma unroll
        for (int n = 0; n < 4; ++n)
            bf[n] = *(const short8*)&lsB[cur][(wc + n * 16 + fr) * 32 + gsw];
        #pragma unroll
        for (int m = 0; m < 4; ++m)
            #pragma unroll
            for (int n = 0; n < 4; ++n)
                acc[m][n] = __builtin_amdgcn_mfma_f32_16x16x32_bf16(af[m], bf[n], acc[m][n], 0, 0, 0);
        __syncthreads();                    // drain prefetch + sync buffer flip
    }

    const int orow = (lane >> 4) * 4;       // C/D: col=lane&15, row=(lane>>4)*4+j  [m89]
    #pragma unroll
    for (int m = 0; m < 4; ++m) {
        #pragma unroll
        for (int n = 0; n < 4; ++n) {
            long gr = row0 + wr + m * 16 + orow;
            long gc = col0 + wc + n * 16 + fr;
            #pragma unroll
            for (int j = 0; j < 4; ++j) {
                float v = acc[m][n][j];
                if (F32OUT) ((float*)Cv)[(gr + j) * N + gc] = v + bias[gc];
                else        ((u16*)  Cv)[(gr + j) * N + gc] = f2bf(v);
            }
        }
    }
}

// ---------------------------------------------------------------------------
// Vs = xb @ Bvs^T : M=16384, N=64, K=1024. 64x64 tile, 4 waves (2x2 of 32x32),
// MFMA 16x16x32, f32 out. 2-phase double-buffer. Grid = 256 blocks.
__global__ __launch_bounds__(256)
void gemm_vs(const u16* __restrict__ A, const u16* __restrict__ Bw,
             float* __restrict__ C)
{
    __shared__ u16 lsA[2][64 * 32];
    __shared__ u16 lsB[2][64 * 32];
    const int tid  = threadIdx.x;
    const int wave = tid >> 6;
    const int lane = tid & 63;
    const long row0 = (long)blockIdx.x * 64;
    const int wr = (wave >> 1) * 32;
    const int wc = (wave & 1) * 32;
    const int fr = lane & 15;
    const int k8 = (lane >> 4) * 8;

    f32x4 acc[2][2] = {};
    const int c0 = tid;                     // one granule-chunk per thread
    const u16* pa = &A [(row0 + (c0 >> 2)) * 1024 + (c0 & 3) * 8];
    const u16* pb = &Bw[((size_t)(c0 >> 2)) * 1024 + (c0 & 3) * 8];

    auto STAGE = [&](int buf, int k0) {
#ifdef HAVE_GLOAD_LDS
        gload_lds16(pa + k0, &lsA[buf][wave * 512]);
        gload_lds16(pb + k0, &lsB[buf][wave * 512]);
#else
        *(short8*)&lsA[buf][(size_t)c0 * 8] = *(const short8*)(pa + k0);
        *(short8*)&lsB[buf][(size_t)c0 * 8] = *(const short8*)(pb + k0);
#endif
    };

    STAGE(0, 0);
    __syncthreads();
    for (int t = 0; t < 32; ++t) {
        const int cur = t & 1;
        if (t + 1 < 32) STAGE(cur ^ 1, (t + 1) << 5);
        short8 af[2], bf[2];
        #pragma unroll
        for (int m = 0; m < 2; ++m)
            af[m] = *(const short8*)&lsA[cur][(wr + m * 16 + fr) * 32 + k8];
        #pragma unroll
        for (int n = 0; n < 2; ++n)
            bf[n] = *(const short8*)&lsB[cur][(wc + n * 16 + fr) * 32 + k8];
        #pragma unroll
        for (int m = 0; m < 2; ++m)
            #pragma unroll
            for (int n = 0; n < 2; ++n)
                acc[m][n] = __builtin_amdgcn_mfma_f32_16x16x32_bf16(af[m], bf[n], acc[m][n], 0, 0, 0);
        __syncthreads();
    }

    const int orow = (lane >> 4) * 4;
    #pragma unroll
    for (int m = 0; m < 2; ++m) {
        #pragma unroll
        for (int n = 0; n < 2; ++n) {
            long gr = row0 + wr + m * 16 + orow;
            int  gc = wc + n * 16 + fr;
            #pragma unroll
            for (int j = 0; j < 4; ++j)
                C[(gr + j) * 64 + gc] = acc[m][n][j];
        }
    }
}

// energy[site][i*16+j] = sum_d Q[site][i*64+d] * K[site][j*64+d], 1 wave/site
// QK stored merged: row stride 2048, Q at +0, K at +1024.
__global__ __launch_bounds__(256)
void energy_kernel(const u16* __restrict__ QKb, float* __restrict__ E)
{
    const int lane = threadIdx.x & 63;
    const size_t site = (size_t)blockIdx.x * 4 + (threadIdx.x >> 6);
    const u16* qrow = QKb + site * 2048;
    const int hh = lane & 15;
    const int kg = (lane >> 4) * 8;
    short8 a0 = *(const short8*)&qrow[hh * 64 + kg];
    short8 a1 = *(const short8*)&qrow[hh * 64 + 32 + kg];
    short8 b0 = *(const short8*)&qrow[1024 + hh * 64 + kg];
    short8 b1 = *(const short8*)&qrow[1024 + hh * 64 + 32 + kg];
    f32x4 acc = {};
    acc = __builtin_amdgcn_mfma_f32_16x16x32_bf16(a0, b0, acc, 0, 0, 0);
    acc = __builtin_amdgcn_mfma_f32_16x16x32_bf16(a1, b1, acc, 0, 0, 0);
    float* out = E + site * 256;
    const int ib = (lane >> 4) * 4;
    #pragma unroll
    for (int r = 0; r < 4; ++r)
        out[(ib + r) * 16 + hh] = acc[r];       // row=i, col=j
}

// ---------------------------------------------------------------------------
// single-pass chunked softmax stats over s: 256 blocks x 64-site chunks.
__global__ __launch_bounds__(256)
void stats_part(const float* __restrict__ E, float* __restrict__ pmax,
                float* __restrict__ psum)
{
    const int b = blockIdx.x, p = threadIdx.x;
    const float* e = E + (size_t)b * 64 * 256 + p;
    float m = -3.4e38f;
    float buf[64];
    #pragma unroll 8
    for (int s = 0; s < 64; ++s) {
        float v = e[(size_t)s * 256];
        buf[s] = v;
        m = fmaxf(m, v);
    }
    float z = 0.f;
    #pragma unroll 8
    for (int s = 0; s < 64; ++s) z += __expf((buf[s] - m) * 0.125f);
    pmax[b * 256 + p] = m;
    psum[b * 256 + p] = z;
}
__global__ __launch_bounds__(256)
void stats_comb(const float* __restrict__ pmax, const float* __restrict__ psum,
                float* __restrict__ gmax, float* __restrict__ invZ)
{
    const int n = blockIdx.x, p = threadIdx.x;
    float m = -3.4e38f;
    #pragma unroll 8
    for (int c = 0; c < 64; ++c) m = fmaxf(m, pmax[(n * 64 + c) * 256 + p]);
    float z = 0.f;
    #pragma unroll 8
    for (int c = 0; c < 64; ++c)
        z += psum[(n * 64 + c) * 256 + p] * __expf((pmax[(n * 64 + c) * 256 + p] - m) * 0.125f);
    gmax[n * 256 + p] = m;
    invZ[n * 256 + p] = 1.0f / z;
}

// A[srow][i] = sum_j exp((E[srow][i*16+j]-m)/8) * invZ
__global__ __launch_bounds__(256)
void a_kernel(const float* __restrict__ E, const float* __restrict__ gmax,
              const float* __restrict__ invZ, float* __restrict__ A)
{
    __shared__ float sm[256], sz[256];
    const int b = blockIdx.x, t = threadIdx.x;
    const int n = b >> 8;
    sm[t] = gmax[n * 256 + t];
    sz[t] = invZ[n * 256 + t];
    __syncthreads();
    const int sl = t >> 4, i = t & 15;
    const size_t srow = (size_t)n * 4096 + (size_t)(b & 255) * 16 + sl;
    const float* e = E + srow * 256 + i * 16;
    float a = 0.f;
    #pragma unroll
    for (int j = 0; j < 16; ++j)
        a += __expf((e[j] - sm[i * 16 + j]) * 0.125f) * sz[i * 16 + j];
    A[srow * 16 + i] = a;
}

// Z2[n][s2][e2] = bf16( A[n][i][s] * Vs[n][s][d] ),  i=s2>>8, s=(s2&255)*16+e2/64, d=e2&63
__global__ __launch_bounds__(256)
void z2_kernel(const float* __restrict__ A, const float* __restrict__ Vs,
               u16* __restrict__ Z2)
{
    const size_t idx = ((size_t)blockIdx.x * 256 + threadIdx.x) * 8;
    const int e2 = (int)(idx & 1023);
    const size_t row = idx >> 10;               // n*4096 + s2
    const int s2 = (int)(row & 4095);
    const int n  = (int)(row >> 12);
    const int i  = s2 >> 8;
    const int s  = ((s2 & 255) << 4) + (e2 >> 6);
    const int d  = e2 & 63;
    const size_t srow = (size_t)n * 4096 + s;
    const float a = A[srow * 16 + i];
    f32x4 v0 = *(const f32x4*)&Vs[srow * 64 + d];
    f32x4 v1 = *(const f32x4*)&Vs[srow * 64 + d + 4];
    u16x8 o;
    o[0]=f2bf(a*v0[0]); o[1]=f2bf(a*v0[1]); o[2]=f2bf(a*v0[2]); o[3]=f2bf(a*v0[3]);
    o[4]=f2bf(a*v1[0]); o[5]=f2bf(a*v1[1]); o[6]=f2bf(a*v1[2]); o[7]=f2bf(a*v1[3]);
    *(u16x8*)&Z2[idx] = o;
}

// ---------------------------------------------------------------------------
extern "C" void kernel_launch(void* const* d_in, const int* in_sizes, int n_in,
                              void* d_out, int out_size, void* d_ws, size_t ws_size,
                              hipStream_t stream)
{
    const float* x  = (const float*)d_in[0];
    const float* Wq = (const float*)d_in[1];
    const float* Wk = (const float*)d_in[2];
    const float* Wv = (const float*)d_in[3];
    const float* Wo = (const float*)d_in[4];
    const float* bo = (const float*)d_in[5];
    float* out = (float*)d_out;
    char* ws = (char*)d_ws;

    u16*   xb   = (u16*)  (ws + OFF_XB);
    float* En   = (float*)(ws + OFF_EN);    // aliases xb (xb dead by then)
    u16*   QKb  = (u16*)  (ws + OFF_QK);    // [16384][2048]: Q | K
    u16*   Z2   = (u16*)  (ws + OFF_QK);    // aliases QKb (dead after energy)
    u16*   Wqb  = (u16*)  (ws + OFF_WQB);   // [Wqb ; Wkb] contiguous = B for merged GEMM
    u16*   Wkb  = (u16*)  (ws + OFF_WKB);
    u16*   Wob  = (u16*)  (ws + OFF_WOB);
    u16*   Bvs  = (u16*)  (ws + OFF_WVST);
    float* Vs   = (float*)(ws + OFF_VS);
    float* gmax = (float*)(ws + OFF_GMAX);
    float* invZ = (float*)(ws + OFF_INVZ);
    float* Ab   = (float*)(ws + OFF_A);
    float* pmax = (float*)(ws + OFF_A);             // alias: dead before A written
    float* psum = (float*)(ws + OFF_A + 262144);    // alias: dead before A written

    // 1. casts + head-reduced bf16 Wv (B^T layout)
    cvt_kernel <<<9728, 256, 0, stream>>>(x, Wq, Wk, Wo, xb, Wqb, Wkb, Wob);
    wvst_kernel<<<256,  256, 0, stream>>>(Wv, Bvs);

    // 2. merged Q|K projection (N=2048) + head-summed V
    gemm_bt<false><<<2048, 256, 0, stream>>>(xb, Wqb, (void*)QKb, nullptr, 16384, 2048, 1024, 4);
    gemm_vs<<<256, 256, 0, stream>>>(xb, Bvs, Vs);

    // 3. per-site 16x16 head-Gram energy (overwrites xb region)
    energy_kernel<<<4096, 256, 0, stream>>>(QKb, En);

    // 4. softmax-over-S stats (single online pass), A, Z2
    stats_part<<<256, 256, 0, stream>>>(En, pmax, psum);
    stats_comb<<<4,   256, 0, stream>>>(pmax, psum, gmax, invZ);
    a_kernel  <<<1024, 256, 0, stream>>>(En, gmax, invZ, Ab);
    z2_kernel <<<8192, 256, 0, stream>>>(Ab, Vs, Z2);

    // 5. output projection + bias -> fp32 d_out
    gemm_bt<true><<<1024, 256, 0, stream>>>(Z2, Wob, (void*)out, bo, 16384, 1024, 1024, 3);
}

// Round 4
// 194.998 us; speedup vs baseline: 1.8524x; 1.1346x over previous
//
#include <hip/hip_runtime.h>
#include <stdint.h>

typedef unsigned short u16;
typedef unsigned int   u32;
typedef __attribute__((ext_vector_type(8))) short short8;
typedef __attribute__((ext_vector_type(4))) float f32x4;
typedef __attribute__((ext_vector_type(8))) u16   u16x8;

// Problem constants: N=4, S=4096, E=1024, H=16, D=64
static constexpr size_t NX = (size_t)4 * 4096 * 1024;   // 16,777,216 x elems
static constexpr size_t NW = (size_t)1024 * 1024;       // 1,048,576 weight elems

// Workspace layout (bytes). energy aliases xb; Z2 aliases QKb; pmax/psum alias A.
static constexpr size_t OFF_XB   = 0;                   // 33,554,432  bf16 x
static constexpr size_t OFF_EN   = 0;                   // 16,777,216  f32 energy [16384][256]
static constexpr size_t OFF_QK   = 33554432;            // 67,108,864  bf16 QK [16384][2048] (later Z2)
static constexpr size_t OFF_WQB  = 100663296;           // 2,097,152  (Wkb contiguous after)
static constexpr size_t OFF_WKB  = 102760448;           // 2,097,152
static constexpr size_t OFF_WOB  = 104857600;           // 2,097,152
static constexpr size_t OFF_WVST = 106954752;           // 131,072  bf16 Bvs [64][1024]
static constexpr size_t OFF_VS   = 107216896;           // 4,194,304 f32 [16384][64]
static constexpr size_t OFF_GMAX = 111411200;           // 4,096
static constexpr size_t OFF_INVZ = 111415296;           // 4,096
static constexpr size_t OFF_A    = 111419392;           // 1,048,576 f32 [16384][16]

static __device__ __forceinline__ u16 f2bf(float f) {
    u32 u = __builtin_bit_cast(u32, f);
    u += 0x7fffu + ((u >> 16) & 1u);        // RNE
    return (u16)(u >> 16);
}
static __device__ __forceinline__ float bf2f(u16 v) {
    u32 u = ((u32)v) << 16;
    return __builtin_bit_cast(float, u);
}

#if __has_builtin(__builtin_amdgcn_global_load_lds)
#define HAVE_GLOAD_LDS 1
static __device__ __forceinline__ void gload_lds16(const void* g, void* l) {
    __builtin_amdgcn_global_load_lds(
        (__attribute__((address_space(1))) void*)(uintptr_t)g,
        (__attribute__((address_space(3))) void*)(uintptr_t)l,
        16, 0, 0);
}
#endif

#if __has_builtin(__builtin_amdgcn_sched_barrier)
#define SCHED_FENCE() __builtin_amdgcn_sched_barrier(0)
#else
#define SCHED_FENCE()
#endif

// ---------------------------------------------------------------------------
// fused fp32 -> bf16 conversion for x, Wq, Wk, Wo
__global__ __launch_bounds__(256)
void cvt_kernel(const float* __restrict__ x, const float* __restrict__ wq,
                const float* __restrict__ wk, const float* __restrict__ wo,
                u16* __restrict__ xb, u16* __restrict__ wqb,
                u16* __restrict__ wkb, u16* __restrict__ wob)
{
    size_t i = ((size_t)blockIdx.x * 256 + threadIdx.x) * 8;
    const float* s; u16* dst; size_t o;
    if (i < NX) { s = x; dst = xb; o = i; }
    else {
        size_t r = i - NX;
        int w = (int)(r >> 20);             // NW = 2^20
        o = r & (NW - 1);
        s   = (w == 0) ? wq  : (w == 1) ? wk  : wo;
        dst = (w == 0) ? wqb : (w == 1) ? wkb : wob;
    }
    f32x4 a = *(const f32x4*)&s[o];
    f32x4 c = *(const f32x4*)&s[o + 4];
    u16x8 v;
    v[0]=f2bf(a[0]); v[1]=f2bf(a[1]); v[2]=f2bf(a[2]); v[3]=f2bf(a[3]);
    v[4]=f2bf(c[0]); v[5]=f2bf(c[1]); v[6]=f2bf(c[2]); v[7]=f2bf(c[3]);
    *(u16x8*)&dst[o] = v;
}

// Bvs[d][e] = bf16( sum_h Wv[(h*64+d)*1024 + e] )   (B^T layout for gemm_vs)
__global__ __launch_bounds__(256)
void wvst_kernel(const float* __restrict__ Wv, u16* __restrict__ Bvs)
{
    int idx = blockIdx.x * 256 + threadIdx.x;   // 65536 total
    int d = idx >> 10;
    int e = idx & 1023;
    float s = 0.f;
    #pragma unroll
    for (int h = 0; h < 16; ++h) s += Wv[(size_t)(h * 64 + d) * 1024 + e];
    Bvs[(size_t)d * 1024 + e] = f2bf(s);
}

// ---------------------------------------------------------------------------
// 256x256-tile 8-wave bf16 GEMM (8-phase structure, T1+T2+T3+T4+T5):
//   C[m][o] = sum_k A[m][k]*B[o][k]   (B^T layout), BK=64, 512 threads.
// Waves 2M x 4N; per-wave output 128x64. LDS 128KB: 2 dbuf x (A 32KB + B 32KB).
// Consumer-staged halves: each wave gload_lds's exactly the A-half/B-half it
// reads (4+4 x 16B per tile), issued in phase0 of the PREVIOUS tile, so the
// boundary __syncthreads (vmcnt(0)) drains ~3-phase-old loads (T4 amortize).
// Granule swizzle (involution, rule #21): LDS slot (row,g) holds global
// granule g^(row&7); reads of logical (row,gl) access slot gl^(row&7).
template<bool F32OUT>
__global__ __launch_bounds__(512, 2)
void gemm_bt8(const u16* __restrict__ A, const u16* __restrict__ Bw,
              void* __restrict__ Cv, const float* __restrict__ bias,
              int M, int N, int K, int lognbx)
{
    __shared__ u16 lds[65536];              // [A: 2x16384][B: 2x16384] u16
    const int tid  = threadIdx.x;
    const int wave = tid >> 6;
    const int lane = tid & 63;

    // T1: XCD-bijective swizzle (gridDim.x % 8 == 0)
    const int nwg = gridDim.x;
    const int swz = ((int)blockIdx.x & 7) * (nwg >> 3) + ((int)blockIdx.x >> 3);
    const long col0 = (long)(swz & ((1 << lognbx) - 1)) * 256;
    const long row0 = (long)(swz >> lognbx) * 256;

    const int wr2 = wave >> 2;              // 0..1 : wave row half
    const int wc2 = wave & 3;               // 0..3 : wave col quarter
    const int fr  = lane & 15;
    const int kq  = lane >> 4;              // 0..3
    const int rxor = fr & 7;

    // ---- staging setup (consumer-staged) ----
    // A-half h (block rows h*128..h*128+127, 16KB) staged by waves with wr2==h.
    const int t255  = tid & 255;
    const int halfA = tid >> 8;             // == wr2
    const int gAsrc = (t255 & 7) ^ ((t255 >> 3) & 7);
    const u16* sA = A + (size_t)(row0 + halfA * 128 + (t255 >> 3)) * K + gAsrc * 8;
    const int dA = halfA * 8192 + t255 * 8; // u16 idx within A buf

    // B-half h (block cols h*128.., 16KB) staged by waves with (wc2>>1)==h.
    const int u  = (tid & 127) | ((tid >> 1) & 128);
    const int bh = (tid >> 7) & 1;          // == wc2>>1
    const int gBsrc = (u & 7) ^ ((u >> 3) & 7);
    const u16* sB = Bw + (size_t)(col0 + bh * 128 + (u >> 3)) * K + gBsrc * 8;
    const int dB = bh * 8192 + u * 8;

    auto STAGE = [&](int buf, int k0) {
        #pragma unroll
        for (int l = 0; l < 4; ++l) {
#ifdef HAVE_GLOAD_LDS
            gload_lds16(sA + (size_t)l * 32 * K + k0, &lds[buf * 16384 + dA + l * 2048]);
            gload_lds16(sB + (size_t)l * 32 * K + k0, &lds[32768 + buf * 16384 + dB + l * 2048]);
#else
            *(short8*)&lds[buf * 16384 + dA + l * 2048] =
                *(const short8*)(sA + (size_t)l * 32 * K + k0);
            *(short8*)&lds[32768 + buf * 16384 + dB + l * 2048] =
                *(const short8*)(sB + (size_t)l * 32 * K + k0);
#endif
        }
    };

    f32x4 acc[8][4] = {};

    STAGE(0, 0);
    __syncthreads();

    const int nt = K >> 6;
    for (int t = 0; t < nt; ++t) {
        const int cur = t & 1;
        const int base  = cur * 16384;
        const int bbase = 32768 + cur * 16384;

        // ---- phase 0: ds-read A-half(mh0) + all B, issue next-tile stages ----
        short8 af[4][2], bf[4][2];
        #pragma unroll
        for (int m = 0; m < 4; ++m) {
            const int row = wr2 * 128 + m * 16 + fr;
            #pragma unroll
            for (int kk = 0; kk < 2; ++kk)
                af[m][kk] = *(const short8*)&lds[base + row * 64 + (((kk << 2) | kq) ^ rxor) * 8];
        }
        #pragma unroll
        for (int n = 0; n < 4; ++n) {
            const int col = wc2 * 64 + n * 16 + fr;
            #pragma unroll
            for (int kk = 0; kk < 2; ++kk)
                bf[n][kk] = *(const short8*)&lds[bbase + col * 64 + (((kk << 2) | kq) ^ rxor) * 8];
        }
        if (t + 1 < nt) STAGE(cur ^ 1, (t + 1) << 6);
        SCHED_FENCE();
        __builtin_amdgcn_s_barrier();

        __builtin_amdgcn_s_setprio(1);
        #pragma unroll
        for (int kk = 0; kk < 2; ++kk)
            #pragma unroll
            for (int m = 0; m < 4; ++m)
                #pragma unroll
                for (int n = 0; n < 2; ++n)
                    acc[m][n] = __builtin_amdgcn_mfma_f32_16x16x32_bf16(af[m][kk], bf[n][kk], acc[m][n], 0, 0, 0);
        __builtin_amdgcn_s_setprio(0);
        __builtin_amdgcn_s_barrier();

        // ---- phase 1: MFMA mh0 x n-half1 ----
        __builtin_amdgcn_s_setprio(1);
        #pragma unroll
        for (int kk = 0; kk < 2; ++kk)
            #pragma unroll
            for (int m = 0; m < 4; ++m)
                #pragma unroll
                for (int n = 2; n < 4; ++n)
                    acc[m][n] = __builtin_amdgcn_mfma_f32_16x16x32_bf16(af[m][kk], bf[n][kk], acc[m][n], 0, 0, 0);
        __builtin_amdgcn_s_setprio(0);

        // ---- phase 2: ds-read A-half(mh1), MFMA mh1 x n-half0 ----
        short8 ag[4][2];
        #pragma unroll
        for (int m = 0; m < 4; ++m) {
            const int row = wr2 * 128 + 64 + m * 16 + fr;
            #pragma unroll
            for (int kk = 0; kk < 2; ++kk)
                ag[m][kk] = *(const short8*)&lds[base + row * 64 + (((kk << 2) | kq) ^ rxor) * 8];
        }
        SCHED_FENCE();
        __builtin_amdgcn_s_barrier();

        __builtin_amdgcn_s_setprio(1);
        #pragma unroll
        for (int kk = 0; kk < 2; ++kk)
            #pragma unroll
            for (int m = 0; m < 4; ++m)
                #pragma unroll
                for (int n = 0; n < 2; ++n)
                    acc[m + 4][n] = __builtin_amdgcn_mfma_f32_16x16x32_bf16(ag[m][kk], bf[n][kk], acc[m + 4][n], 0, 0, 0);
        __builtin_amdgcn_s_setprio(0);
        __builtin_amdgcn_s_barrier();

        // ---- phase 3: MFMA mh1 x n-half1 ----
        __builtin_amdgcn_s_setprio(1);
        #pragma unroll
        for (int kk = 0; kk < 2; ++kk)
            #pragma unroll
            for (int m = 0; m < 4; ++m)
                #pragma unroll
                for (int n = 2; n < 4; ++n)
                    acc[m + 4][n] = __builtin_amdgcn_mfma_f32_16x16x32_bf16(ag[m][kk], bf[n][kk], acc[m + 4][n], 0, 0, 0);
        __builtin_amdgcn_s_setprio(0);

        __syncthreads();    // boundary: drain own stage loads (3 phases old) + flip
    }

    // epilogue: C/D col=lane&15, row=(lane>>4)*4+j  [m89]
    #pragma unroll
    for (int m = 0; m < 8; ++m) {
        #pragma unroll
        for (int n = 0; n < 4; ++n) {
            long gr = row0 + wr2 * 128 + m * 16 + kq * 4;
            long gc = col0 + wc2 * 64 + n * 16 + fr;
            #pragma unroll
            for (int j = 0; j < 4; ++j) {
                float v = acc[m][n][j];
                if (F32OUT) ((float*)Cv)[(gr + j) * N + gc] = v + bias[gc];
                else        ((u16*)  Cv)[(gr + j) * N + gc] = f2bf(v);
            }
        }
    }
}

// ---------------------------------------------------------------------------
// Vs = xb @ Bvs^T : M=16384, N=64, K=1024. 64x64 tile, 4 waves (2x2 of 32x32),
// MFMA 16x16x32, f32 out. 2-phase double-buffer. Grid = 256 blocks.
__global__ __launch_bounds__(256)
void gemm_vs(const u16* __restrict__ A, const u16* __restrict__ Bw,
             float* __restrict__ C)
{
    __shared__ u16 lsA[2][64 * 32];
    __shared__ u16 lsB[2][64 * 32];
    const int tid  = threadIdx.x;
    const int wave = tid >> 6;
    const int lane = tid & 63;
    const long row0 = (long)blockIdx.x * 64;
    const int wr = (wave >> 1) * 32;
    const int wc = (wave & 1) * 32;
    const int fr = lane & 15;
    const int k8 = (lane >> 4) * 8;

    f32x4 acc[2][2] = {};
    const int c0 = tid;
    const u16* pa = &A [(row0 + (c0 >> 2)) * 1024 + (c0 & 3) * 8];
    const u16* pb = &Bw[((size_t)(c0 >> 2)) * 1024 + (c0 & 3) * 8];

    auto STAGE = [&](int buf, int k0) {
#ifdef HAVE_GLOAD_LDS
        gload_lds16(pa + k0, &lsA[buf][wave * 512]);
        gload_lds16(pb + k0, &lsB[buf][wave * 512]);
#else
        *(short8*)&lsA[buf][(size_t)c0 * 8] = *(const short8*)(pa + k0);
        *(short8*)&lsB[buf][(size_t)c0 * 8] = *(const short8*)(pb + k0);
#endif
    };

    STAGE(0, 0);
    __syncthreads();
    for (int t = 0; t < 32; ++t) {
        const int cur = t & 1;
        if (t + 1 < 32) STAGE(cur ^ 1, (t + 1) << 5);
        short8 af[2], bf[2];
        #pragma unroll
        for (int m = 0; m < 2; ++m)
            af[m] = *(const short8*)&lsA[cur][(wr + m * 16 + fr) * 32 + k8];
        #pragma unroll
        for (int n = 0; n < 2; ++n)
            bf[n] = *(const short8*)&lsB[cur][(wc + n * 16 + fr) * 32 + k8];
        #pragma unroll
        for (int m = 0; m < 2; ++m)
            #pragma unroll
            for (int n = 0; n < 2; ++n)
                acc[m][n] = __builtin_amdgcn_mfma_f32_16x16x32_bf16(af[m], bf[n], acc[m][n], 0, 0, 0);
        __syncthreads();
    }

    const int orow = (lane >> 4) * 4;
    #pragma unroll
    for (int m = 0; m < 2; ++m) {
        #pragma unroll
        for (int n = 0; n < 2; ++n) {
            long gr = row0 + wr + m * 16 + orow;
            int  gc = wc + n * 16 + fr;
            #pragma unroll
            for (int j = 0; j < 4; ++j)
                C[(gr + j) * 64 + gc] = acc[m][n][j];
        }
    }
}

// energy[site][i*16+j] = sum_d Q[site][i*64+d] * K[site][j*64+d], 1 wave/site
// QK stored merged: row stride 2048, Q at +0, K at +1024.
__global__ __launch_bounds__(256)
void energy_kernel(const u16* __restrict__ QKb, float* __restrict__ E)
{
    const int lane = threadIdx.x & 63;
    const size_t site = (size_t)blockIdx.x * 4 + (threadIdx.x >> 6);
    const u16* qrow = QKb + site * 2048;
    const int hh = lane & 15;
    const int kg = (lane >> 4) * 8;
    short8 a0 = *(const short8*)&qrow[hh * 64 + kg];
    short8 a1 = *(const short8*)&qrow[hh * 64 + 32 + kg];
    short8 b0 = *(const short8*)&qrow[1024 + hh * 64 + kg];
    short8 b1 = *(const short8*)&qrow[1024 + hh * 64 + 32 + kg];
    f32x4 acc = {};
    acc = __builtin_amdgcn_mfma_f32_16x16x32_bf16(a0, b0, acc, 0, 0, 0);
    acc = __builtin_amdgcn_mfma_f32_16x16x32_bf16(a1, b1, acc, 0, 0, 0);
    float* out = E + site * 256;
    const int ib = (lane >> 4) * 4;
    #pragma unroll
    for (int r = 0; r < 4; ++r)
        out[(ib + r) * 16 + hh] = acc[r];       // row=i, col=j
}

// ---------------------------------------------------------------------------
// single-pass chunked softmax stats over s: 256 blocks x 64-site chunks.
__global__ __launch_bounds__(256)
void stats_part(const float* __restrict__ E, float* __restrict__ pmax,
                float* __restrict__ psum)
{
    const int b = blockIdx.x, p = threadIdx.x;
    const float* e = E + (size_t)b * 64 * 256 + p;
    float m = -3.4e38f;
    float buf[64];
    #pragma unroll 8
    for (int s = 0; s < 64; ++s) {
        float v = e[(size_t)s * 256];
        buf[s] = v;
        m = fmaxf(m, v);
    }
    float z = 0.f;
    #pragma unroll 8
    for (int s = 0; s < 64; ++s) z += __expf((buf[s] - m) * 0.125f);
    pmax[b * 256 + p] = m;
    psum[b * 256 + p] = z;
}
__global__ __launch_bounds__(256)
void stats_comb(const float* __restrict__ pmax, const float* __restrict__ psum,
                float* __restrict__ gmax, float* __restrict__ invZ)
{
    const int n = blockIdx.x, p = threadIdx.x;
    float m = -3.4e38f;
    #pragma unroll 8
    for (int c = 0; c < 64; ++c) m = fmaxf(m, pmax[(n * 64 + c) * 256 + p]);
    float z = 0.f;
    #pragma unroll 8
    for (int c = 0; c < 64; ++c)
        z += psum[(n * 64 + c) * 256 + p] * __expf((pmax[(n * 64 + c) * 256 + p] - m) * 0.125f);
    gmax[n * 256 + p] = m;
    invZ[n * 256 + p] = 1.0f / z;
}

// A[srow][i] = sum_j exp((E[srow][i*16+j]-m)/8) * invZ
__global__ __launch_bounds__(256)
void a_kernel(const float* __restrict__ E, const float* __restrict__ gmax,
              const float* __restrict__ invZ, float* __restrict__ A)
{
    __shared__ float sm[256], sz[256];
    const int b = blockIdx.x, t = threadIdx.x;
    const int n = b >> 8;
    sm[t] = gmax[n * 256 + t];
    sz[t] = invZ[n * 256 + t];
    __syncthreads();
    const int sl = t >> 4, i = t & 15;
    const size_t srow = (size_t)n * 4096 + (size_t)(b & 255) * 16 + sl;
    const float* e = E + srow * 256 + i * 16;
    float a = 0.f;
    #pragma unroll
    for (int j = 0; j < 16; ++j)
        a += __expf((e[j] - sm[i * 16 + j]) * 0.125f) * sz[i * 16 + j];
    A[srow * 16 + i] = a;
}

// Z2[n][s2][e2] = bf16( A[n][i][s] * Vs[n][s][d] ),  i=s2>>8, s=(s2&255)*16+e2/64, d=e2&63
__global__ __launch_bounds__(256)
void z2_kernel(const float* __restrict__ A, const float* __restrict__ Vs,
               u16* __restrict__ Z2)
{
    const size_t idx = ((size_t)blockIdx.x * 256 + threadIdx.x) * 8;
    const int e2 = (int)(idx & 1023);
    const size_t row = idx >> 10;               // n*4096 + s2
    const int s2 = (int)(row & 4095);
    const int n  = (int)(row >> 12);
    const int i  = s2 >> 8;
    const int s  = ((s2 & 255) << 4) + (e2 >> 6);
    const int d  = e2 & 63;
    const size_t srow = (size_t)n * 4096 + s;
    const float a = A[srow * 16 + i];
    f32x4 v0 = *(const f32x4*)&Vs[srow * 64 + d];
    f32x4 v1 = *(const f32x4*)&Vs[srow * 64 + d + 4];
    u16x8 o;
    o[0]=f2bf(a*v0[0]); o[1]=f2bf(a*v0[1]); o[2]=f2bf(a*v0[2]); o[3]=f2bf(a*v0[3]);
    o[4]=f2bf(a*v1[0]); o[5]=f2bf(a*v1[1]); o[6]=f2bf(a*v1[2]); o[7]=f2bf(a*v1[3]);
    *(u16x8*)&Z2[idx] = o;
}

// ---------------------------------------------------------------------------
extern "C" void kernel_launch(void* const* d_in, const int* in_sizes, int n_in,
                              void* d_out, int out_size, void* d_ws, size_t ws_size,
                              hipStream_t stream)
{
    const float* x  = (const float*)d_in[0];
    const float* Wq = (const float*)d_in[1];
    const float* Wk = (const float*)d_in[2];
    const float* Wv = (const float*)d_in[3];
    const float* Wo = (const float*)d_in[4];
    const float* bo = (const float*)d_in[5];
    float* out = (float*)d_out;
    char* ws = (char*)d_ws;

    u16*   xb   = (u16*)  (ws + OFF_XB);
    float* En   = (float*)(ws + OFF_EN);    // aliases xb (xb dead by then)
    u16*   QKb  = (u16*)  (ws + OFF_QK);    // [16384][2048]: Q | K
    u16*   Z2   = (u16*)  (ws + OFF_QK);    // aliases QKb (dead after energy)
    u16*   Wqb  = (u16*)  (ws + OFF_WQB);   // [Wqb ; Wkb] contiguous = B for merged GEMM
    u16*   Wkb  = (u16*)  (ws + OFF_WKB);
    u16*   Wob  = (u16*)  (ws + OFF_WOB);
    u16*   Bvs  = (u16*)  (ws + OFF_WVST);
    float* Vs   = (float*)(ws + OFF_VS);
    float* gmax = (float*)(ws + OFF_GMAX);
    float* invZ = (float*)(ws + OFF_INVZ);
    float* Ab   = (float*)(ws + OFF_A);
    float* pmax = (float*)(ws + OFF_A);             // alias: dead before A written
    float* psum = (float*)(ws + OFF_A + 262144);    // alias: dead before A written

    // 1. casts + head-reduced bf16 Wv (B^T layout)
    cvt_kernel <<<9728, 256, 0, stream>>>(x, Wq, Wk, Wo, xb, Wqb, Wkb, Wob);
    wvst_kernel<<<256,  256, 0, stream>>>(Wv, Bvs);

    // 2. merged Q|K projection (N=2048, 8x64=512 blocks) + head-summed V
    gemm_bt8<false><<<512, 512, 0, stream>>>(xb, Wqb, (void*)QKb, nullptr, 16384, 2048, 1024, 3);
    gemm_vs<<<256, 256, 0, stream>>>(xb, Bvs, Vs);

    // 3. per-site 16x16 head-Gram energy (overwrites xb region)
    energy_kernel<<<4096, 256, 0, stream>>>(QKb, En);

    // 4. softmax-over-S stats (single online pass), A, Z2
    stats_part<<<256, 256, 0, stream>>>(En, pmax, psum);
    stats_comb<<<4,   256, 0, stream>>>(pmax, psum, gmax, invZ);
    a_kernel  <<<1024, 256, 0, stream>>>(En, gmax, invZ, Ab);
    z2_kernel <<<8192, 256, 0, stream>>>(Ab, Vs, Z2);

    // 5. output projection + bias -> fp32 d_out (4x64=256 blocks)
    gemm_bt8<true><<<256, 512, 0, stream>>>(Z2, Wob, (void*)out, bo, 16384, 1024, 1024, 2);
}